// Round 8
// baseline (386.369 us; speedup 1.0000x reference)
//
#include <hip/hip_runtime.h>
#include <hip/hip_bf16.h>

// ---------- problem constants ----------
#define N_NODES 50000
#define N_EDGES 800000
#define C_DIM   256      // IN_C == HID_C
#define OUT_C   128
#define N_GRAPHS 256

typedef unsigned short ushort8 __attribute__((ext_vector_type(8)));
typedef __bf16         bf16x8  __attribute__((ext_vector_type(8)));
typedef float          f32x4   __attribute__((ext_vector_type(4)));

#if __has_builtin(__builtin_amdgcn_sched_barrier)
#define SCHED_FENCE() __builtin_amdgcn_sched_barrier(0)
#else
#define SCHED_FENCE() ((void)0)
#endif

__device__ __forceinline__ float us2f(unsigned short u) {
    unsigned int x = ((unsigned int)u) << 16;
    return __builtin_bit_cast(float, x);
}
__device__ __forceinline__ unsigned short f2bf(float f) {
    unsigned int u = __builtin_bit_cast(unsigned int, f);
    u += 0x7fffu + ((u >> 16) & 1u);   // RNE
    return (unsigned short)(u >> 16);
}

__device__ __forceinline__ int lower_bound_i(const int* __restrict__ a, int n, int v) {
    int lo = 0, hi = n;
    while (lo < hi) {
        int mid = (lo + hi) >> 1;
        if (a[mid] < v) lo = mid + 1; else hi = mid;
    }
    return lo;
}

// ---------- K1: merged preprocess ----------
__global__ void preprocess(const float* __restrict__ x, unsigned short* __restrict__ xb,
                           const float* __restrict__ W0, const float* __restrict__ W1,
                           const float* __restrict__ W2, const float* __restrict__ W3,
                           unsigned short* __restrict__ D0, unsigned short* __restrict__ D1,
                           unsigned short* __restrict__ D2, unsigned short* __restrict__ D3,
                           const int* __restrict__ dst, const int* __restrict__ batch,
                           int* __restrict__ row_ptr, int* __restrict__ graph_ptr,
                           float* __restrict__ inv_deg) {
    int b = blockIdx.x;
    int t = threadIdx.x;
    if (b < 12500) {
        int i = b * 256 + t;                 // group of 4 elements
        float4 v = *(const float4*)(x + ((size_t)i << 2));
        ushort4 o;
        o.x = f2bf(v.x); o.y = f2bf(v.y); o.z = f2bf(v.z); o.w = f2bf(v.w);
        *(ushort4*)(xb + ((size_t)i << 2)) = o;
    } else if (b < 13524) {
        int sub = b - 12500;
        const float* S; unsigned short* D;
        switch (sub >> 8) {
            case 0: S = W0; D = D0; break;
            case 1: S = W1; D = D1; break;
            case 2: S = W2; D = D2; break;
            default: S = W3; D = D3; break;
        }
        int i = (sub & 255) * 256 + t;       // i = k*256 + n
        int k = i >> 8, n = i & 255;
        D[n * 256 + k] = f2bf(S[i]);
    } else {
        int i = (b - 13524) * 256 + t;
        if (i <= N_NODES) {
            int lb = lower_bound_i(dst, N_EDGES, i);
            row_ptr[i] = lb;
            if (i < N_NODES) {
                int ub = lower_bound_i(dst, N_EDGES, i + 1);
                int cnt = ub - lb;
                inv_deg[i] = (cnt > 0) ? (1.0f / (float)cnt) : 0.0f;
            }
        }
        if (i <= N_GRAPHS) graph_ptr[i] = lower_bound_i(batch, N_NODES, i);
    }
}

// ---------- K2: FUSED conv: gather-mean + (agg@Bl + X@Br + bias [, relu]) ----------
// Block = 64 node-rows x full N=256. Phase 1: 4 waves gather/mean 16 rows each
// (bursted, scalar-base loads) -> bf16 -> XOR-swizzled LDS agg tile (32 KB).
// Phase 2: K-loop; A-frags from LDS (iters 0-3) / direct global xb (iters 4-7),
// B-frags direct global (L2-resident 256 KB). No other LDS staging -> 3 blk/CU,
// gather phase of one block overlaps MFMA phase of co-resident blocks.
__global__ __launch_bounds__(256, 3)
void conv_fused(const unsigned short* __restrict__ X,     // node features [M x 256] bf16
                const int* __restrict__ src,
                const int* __restrict__ row_ptr,
                const float* __restrict__ inv_deg,
                const unsigned short* __restrict__ Blt,   // Wl^T [256n x 256k] bf16
                const unsigned short* __restrict__ Brt,   // Wr^T [256n x 256k] bf16
                const float* __restrict__ bias,
                unsigned short* __restrict__ C,
                int do_relu) {
    __shared__ __align__(16) unsigned short Agg[16384];   // 64 rows x 32 chunks x 8

    const int t    = threadIdx.x;
    const int m0   = blockIdx.x * 64;
    const int lane = t & 63, wid = t >> 6;
    const int lo   = lane << 2;              // channel offset (4 ch/lane)

    // ---- Phase 1: aggregate rows m0+wid*16 .. +15 ----
    for (int rr = 0; rr < 16; ++rr) {
        int r  = wid * 16 + rr;              // local row
        int gw = m0 + r;
        float a0 = 0.f, a1 = 0.f, a2 = 0.f, a3 = 0.f;
        float sc = 0.f;
        if (gw < N_NODES) {
            int e0 = row_ptr[gw], e1 = row_ptr[gw + 1];
            sc = inv_deg[gw];
            int e = e0;
            for (; e + 16 <= e1; e += 16) {
                ushort4 v[16];
#pragma unroll
                for (int j = 0; j < 16; ++j) {
                    int s = __builtin_amdgcn_readfirstlane(src[e + j]);
                    v[j] = *(const ushort4*)(X + ((size_t)s << 8) + lo);
                }
                SCHED_FENCE();
#pragma unroll
                for (int j = 0; j < 16; ++j) {
                    a0 += us2f(v[j].x); a1 += us2f(v[j].y);
                    a2 += us2f(v[j].z); a3 += us2f(v[j].w);
                }
            }
            if (e < e1) {                    // clamped burst of 16
                int cl = e1 - 1;
                ushort4 v[16]; float w[16];
#pragma unroll
                for (int j = 0; j < 16; ++j) {
                    int ej = e + j;
                    int ec = ej < cl ? ej : cl;
                    w[j] = (ej < e1) ? 1.0f : 0.0f;
                    int s = __builtin_amdgcn_readfirstlane(src[ec]);
                    v[j] = *(const ushort4*)(X + ((size_t)s << 8) + lo);
                }
                SCHED_FENCE();
#pragma unroll
                for (int j = 0; j < 16; ++j) {
                    a0 = fmaf(us2f(v[j].x), w[j], a0);
                    a1 = fmaf(us2f(v[j].y), w[j], a1);
                    a2 = fmaf(us2f(v[j].z), w[j], a2);
                    a3 = fmaf(us2f(v[j].w), w[j], a3);
                }
            }
        }
        // write bf16x4 (8B) to swizzled LDS: chunk c = lane>>1, half = lane&1
        ushort4 o;
        o.x = f2bf(a0 * sc); o.y = f2bf(a1 * sc);
        o.z = f2bf(a2 * sc); o.w = f2bf(a3 * sc);
        int c    = lane >> 1;
        int slot = r * 32 + (c ^ (r & 31));
        *(ushort4*)(Agg + slot * 8 + (lane & 1) * 4) = o;
    }
    __syncthreads();

    // ---- Phase 2: GEMM ----
    const int wn   = wid * 64;               // wave n-offset {0,64,128,192}
    const int lrow = lane & 15;
    const int kq   = lane >> 4;              // 0..3

    const f32x4 zero4 = {0.f, 0.f, 0.f, 0.f};
    f32x4 acc[4][4];
#pragma unroll
    for (int i = 0; i < 4; ++i)
#pragma unroll
        for (int j = 0; j < 4; ++j) acc[i][j] = zero4;

    for (int it = 0; it < 8; ++it) {         // K = 512 virtual (agg:0-3, X:4-7)
        const unsigned short* __restrict__ Bb = (it < 4) ? Blt : Brt;
        int ko = (it * 64) & 255;            // k-offset within 256

#pragma unroll
        for (int s = 0; s < 2; ++s) {
            int kk = ko + s * 32 + kq * 8;   // global k of this quad's 8-slice
            bf16x8 af[4], bfr[4];
            if (it < 4) {
                int c = kk >> 3;             // chunk index 0..31
#pragma unroll
                for (int mi = 0; mi < 4; ++mi) {
                    int r = mi * 16 + lrow;
                    int slot = r * 32 + (c ^ (r & 31));
                    uint4 u = *(const uint4*)(Agg + slot * 8);
                    af[mi] = __builtin_bit_cast(bf16x8, u);
                }
            } else {
#pragma unroll
                for (int mi = 0; mi < 4; ++mi) {
                    int m = m0 + mi * 16 + lrow;   // tail rows read past M into
                    uint4 u = *(const uint4*)(X + (size_t)m * 256 + kk); // next slab
                    af[mi] = __builtin_bit_cast(bf16x8, u);
                }
            }
#pragma unroll
            for (int ni = 0; ni < 4; ++ni) {
                int n = wn + ni * 16 + lrow;
                uint4 u = *(const uint4*)(Bb + (size_t)n * 256 + kk);
                bfr[ni] = __builtin_bit_cast(bf16x8, u);
            }
#pragma unroll
            for (int mi = 0; mi < 4; ++mi)
#pragma unroll
                for (int ni = 0; ni < 4; ++ni)
                    acc[mi][ni] = __builtin_amdgcn_mfma_f32_16x16x32_bf16(
                        af[mi], bfr[ni], acc[mi][ni], 0, 0, 0);
        }
    }

    // epilogue: D mapping col = lane&15, row = (lane>>4)*4 + reg
    const int rbase = (lane >> 4) * 4;
#pragma unroll
    for (int ni = 0; ni < 4; ++ni) {
        int n  = wn + ni * 16 + lrow;
        float bv = bias[n];
#pragma unroll
        for (int mi = 0; mi < 4; ++mi) {
            int mb = m0 + mi * 16 + rbase;
#pragma unroll
            for (int r = 0; r < 4; ++r) {
                int m = mb + r;
                if (m < N_NODES) {
                    float v = acc[mi][ni][r] + bv;
                    if (do_relu) v = fmaxf(v, 0.f);
                    C[(size_t)m * 256 + n] = f2bf(v);
                }
            }
        }
    }
}

// ---------- K3: fused pool + root gather + final linear ----------
__global__ void pool_final(const unsigned short* __restrict__ h2,
                           const float* __restrict__ p,
                           const int* __restrict__ graph_ptr,
                           const int* __restrict__ root_ptr,
                           const float* __restrict__ Wlin,
                           const float* __restrict__ blin,
                           float* __restrict__ out) {
    __shared__ float fl[512];
    int g = blockIdx.x;
    int c = threadIdx.x;        // 256 threads = channels
    int s = graph_ptr[g], e = graph_ptr[g + 1];
    float acc = 0.f;
    for (int n = s; n < e; n += 8) {
        int cl = e - 1;
        float w[8]; unsigned short v[8];
#pragma unroll
        for (int j = 0; j < 8; ++j) {
            int nj = n + j;
            int ncj = nj < cl ? nj : cl;
            int nu = __builtin_amdgcn_readfirstlane(ncj);
            w[j] = (nj < e) ? p[nu] : 0.0f;
            v[j] = h2[(size_t)nu * 256 + c];
        }
        SCHED_FENCE();
#pragma unroll
        for (int j = 0; j < 8; ++j)
            acc = fmaf(us2f(v[j]), w[j], acc);
    }
    float cnt = (float)(e - s);
    int root = root_ptr[g];
    fl[c]       = us2f(h2[(size_t)root * 256 + c]);
    fl[256 + c] = acc / fmaxf(cnt, 1.0f);
    __syncthreads();

    int o = threadIdx.x;
    if (o < 128) {
        float s0 = 0.f, s1 = 0.f, s2 = 0.f, s3 = 0.f;
        for (int k = 0; k < 512; k += 4) {
            s0 = fmaf(fl[k + 0], Wlin[(k + 0) * 128 + o], s0);
            s1 = fmaf(fl[k + 1], Wlin[(k + 1) * 128 + o], s1);
            s2 = fmaf(fl[k + 2], Wlin[(k + 2) * 128 + o], s2);
            s3 = fmaf(fl[k + 3], Wlin[(k + 3) * 128 + o], s3);
        }
        out[(size_t)g * 128 + o] = blin[o] + ((s0 + s1) + (s2 + s3));
    }
}

extern "C" void kernel_launch(void* const* d_in, const int* in_sizes, int n_in,
                              void* d_out, int out_size, void* d_ws, size_t ws_size,
                              hipStream_t stream) {
    const float* x        = (const float*)d_in[0];
    const int*   src      = (const int*)d_in[1];
    const int*   dst      = (const int*)d_in[2];
    const float* p        = (const float*)d_in[3];
    const int*   batch    = (const int*)d_in[4];
    const int*   root_ptr = (const int*)d_in[5];
    // d_in[6] = num_graphs (256, hard-coded)
    const float* Wl1  = (const float*)d_in[7];
    const float* Wr1  = (const float*)d_in[8];
    const float* b1   = (const float*)d_in[9];
    const float* Wl2  = (const float*)d_in[10];
    const float* Wr2  = (const float*)d_in[11];
    const float* b2   = (const float*)d_in[12];
    const float* Wlin = (const float*)d_in[13];
    const float* blin = (const float*)d_in[14];
    float* out = (float*)d_out;

    // workspace layout (256B aligned slabs)
    size_t off = 0;
    char* base = (char*)d_ws;
    auto alloc = [&](size_t bytes) -> void* {
        void* q = base + off;
        off += (bytes + 255) & ~(size_t)255;
        return q;
    };
    int*            row_ptr   = (int*)  alloc((N_NODES + 1) * sizeof(int));
    int*            graph_ptr = (int*)  alloc((N_GRAPHS + 1) * sizeof(int));
    float*          inv_deg   = (float*)alloc(N_NODES * sizeof(float));
    unsigned short* Wl1t = (unsigned short*)alloc(256 * 256 * 2);
    unsigned short* Wr1t = (unsigned short*)alloc(256 * 256 * 2);
    unsigned short* Wl2t = (unsigned short*)alloc(256 * 256 * 2);
    unsigned short* Wr2t = (unsigned short*)alloc(256 * 256 * 2);
    unsigned short* xb   = (unsigned short*)alloc((size_t)N_NODES * 256 * 2);
    unsigned short* h1   = (unsigned short*)alloc((size_t)N_NODES * 256 * 2);
    unsigned short* h2   = (unsigned short*)alloc((size_t)N_NODES * 256 * 2);
    (void)ws_size; (void)n_in; (void)in_sizes; (void)out_size;

    preprocess<<<13720, 256, 0, stream>>>(x, xb, Wl1, Wr1, Wl2, Wr2,
                                          Wl1t, Wr1t, Wl2t, Wr2t,
                                          dst, batch, row_ptr, graph_ptr, inv_deg);

    dim3 cgrid((N_NODES + 63) / 64);

    // conv1: h1 = relu(agg(x)@Wl1 + x@Wr1 + b1)
    conv_fused<<<cgrid, 256, 0, stream>>>(xb, src, row_ptr, inv_deg,
                                          Wl1t, Wr1t, b1, h1, 1);
    // conv2: h2 = agg(h1)@Wl2 + h1@Wr2 + b2
    conv_fused<<<cgrid, 256, 0, stream>>>(h1, src, row_ptr, inv_deg,
                                          Wl2t, Wr2t, b2, h2, 0);

    // fused pool + root gather + final linear
    pool_final<<<N_GRAPHS, 256, 0, stream>>>(h2, p, graph_ptr, root_ptr,
                                             Wlin, blin, out);
}

// Round 9
// 316.779 us; speedup vs baseline: 1.2197x; 1.2197x over previous
//
#include <hip/hip_runtime.h>
#include <hip/hip_bf16.h>

// ---------- problem constants ----------
#define N_NODES 50000
#define N_EDGES 800000
#define C_DIM   256      // IN_C == HID_C
#define OUT_C   128
#define N_GRAPHS 256

typedef unsigned short ushort8 __attribute__((ext_vector_type(8)));
typedef __bf16         bf16x8  __attribute__((ext_vector_type(8)));
typedef float          f32x4   __attribute__((ext_vector_type(4)));

typedef __attribute__((address_space(1))) const unsigned int gu32;
typedef __attribute__((address_space(3))) unsigned int lu32;

#if __has_builtin(__builtin_amdgcn_sched_barrier)
#define SCHED_FENCE() __builtin_amdgcn_sched_barrier(0)
#else
#define SCHED_FENCE() ((void)0)
#endif

__device__ __forceinline__ float us2f(unsigned short u) {
    unsigned int x = ((unsigned int)u) << 16;
    return __builtin_bit_cast(float, x);
}
__device__ __forceinline__ unsigned short f2bf(float f) {
    unsigned int u = __builtin_bit_cast(unsigned int, f);
    u += 0x7fffu + ((u >> 16) & 1u);   // RNE
    return (unsigned short)(u >> 16);
}

__device__ __forceinline__ int lower_bound_i(const int* __restrict__ a, int n, int v) {
    int lo = 0, hi = n;
    while (lo < hi) {
        int mid = (lo + hi) >> 1;
        if (a[mid] < v) lo = mid + 1; else hi = mid;
    }
    return lo;
}

// ---------- K1: merged preprocess ----------
__global__ void preprocess(const float* __restrict__ x, unsigned short* __restrict__ xb,
                           const float* __restrict__ W0, const float* __restrict__ W1,
                           const float* __restrict__ W2, const float* __restrict__ W3,
                           unsigned short* __restrict__ D0, unsigned short* __restrict__ D1,
                           unsigned short* __restrict__ D2, unsigned short* __restrict__ D3,
                           const int* __restrict__ dst, const int* __restrict__ batch,
                           int* __restrict__ row_ptr, int* __restrict__ graph_ptr,
                           float* __restrict__ inv_deg) {
    int b = blockIdx.x;
    int t = threadIdx.x;
    if (b < 12500) {
        int i = b * 256 + t;                 // group of 4 elements
        float4 v = *(const float4*)(x + ((size_t)i << 2));
        ushort4 o;
        o.x = f2bf(v.x); o.y = f2bf(v.y); o.z = f2bf(v.z); o.w = f2bf(v.w);
        *(ushort4*)(xb + ((size_t)i << 2)) = o;
    } else if (b < 13524) {
        int sub = b - 12500;
        const float* S; unsigned short* D;
        switch (sub >> 8) {
            case 0: S = W0; D = D0; break;
            case 1: S = W1; D = D1; break;
            case 2: S = W2; D = D2; break;
            default: S = W3; D = D3; break;
        }
        int i = (sub & 255) * 256 + t;       // i = k*256 + n
        int k = i >> 8, n = i & 255;
        D[n * 256 + k] = f2bf(S[i]);
    } else {
        int i = (b - 13524) * 256 + t;
        if (i <= N_NODES) {
            int lb = lower_bound_i(dst, N_EDGES, i);
            row_ptr[i] = lb;
            if (i < N_NODES) {
                int ub = lower_bound_i(dst, N_EDGES, i + 1);
                int cnt = ub - lb;
                inv_deg[i] = (cnt > 0) ? (1.0f / (float)cnt) : 0.0f;
            }
        }
        if (i <= N_GRAPHS) graph_ptr[i] = lower_bound_i(batch, N_NODES, i);
    }
}

// ---------- K2: mean aggregation (bf16 in/out, f32 accum) ----------
// AT STRUCTURAL CEILING (rounds 3-8: four different structures all ~57 µs,
// FETCH=175 MB @ ~3.6 TB/s; fusion into the GEMM regressed by halving the
// resident gather-wave count). One wave per node, scalar-base gathers,
// 16-deep fenced bursts. DO NOT fold into another kernel.
__global__ void aggregate(const unsigned short* __restrict__ X,
                          const int* __restrict__ src,
                          const int* __restrict__ row_ptr,
                          const float* __restrict__ inv_deg,
                          unsigned short* __restrict__ out) {
    int gw   = (blockIdx.x * blockDim.x + threadIdx.x) >> 6;
    int lane = threadIdx.x & 63;
    if (gw >= N_NODES) return;
    int e0 = row_ptr[gw], e1 = row_ptr[gw + 1];
    const int lo = lane << 2;
    float a0 = 0.f, a1 = 0.f, a2 = 0.f, a3 = 0.f;
    int e = e0;

    for (; e + 16 <= e1; e += 16) {
        ushort4 v[16];
#pragma unroll
        for (int j = 0; j < 16; ++j) {
            int s = __builtin_amdgcn_readfirstlane(src[e + j]);
            v[j] = *(const ushort4*)(X + ((size_t)s << 8) + lo);
        }
        SCHED_FENCE();
#pragma unroll
        for (int j = 0; j < 16; ++j) {
            a0 += us2f(v[j].x); a1 += us2f(v[j].y);
            a2 += us2f(v[j].z); a3 += us2f(v[j].w);
        }
    }
    int rem = e1 - e;
    if (rem > 0) {
        int cl = e1 - 1;
        ushort4 v[16]; float w[16];
#pragma unroll
        for (int j = 0; j < 16; ++j) {
            int ej = e + j;
            int ec = ej < cl ? ej : cl;
            w[j] = (ej < e1) ? 1.0f : 0.0f;
            int s = __builtin_amdgcn_readfirstlane(src[ec]);
            v[j] = *(const ushort4*)(X + ((size_t)s << 8) + lo);
        }
        SCHED_FENCE();
#pragma unroll
        for (int j = 0; j < 16; ++j) {
            a0 = fmaf(us2f(v[j].x), w[j], a0);
            a1 = fmaf(us2f(v[j].y), w[j], a1);
            a2 = fmaf(us2f(v[j].z), w[j], a2);
            a3 = fmaf(us2f(v[j].w), w[j], a3);
        }
    }

    float sc = inv_deg[gw];
    ushort4 o;
    o.x = f2bf(a0 * sc); o.y = f2bf(a1 * sc); o.z = f2bf(a2 * sc); o.w = f2bf(a3 * sc);
    *(ushort4*)(out + ((size_t)gw << 8) + lo) = o;
}

// ---------- K3: fused SAGE GEMM (round-6 shape — measured best) ----------
// One block = 128-row strip x FULL N=256 (A rows read once). 512 threads =
// 8 waves (2m x 4n), each wave 4x4 MFMA 16x16x32, BK=64 (8 barrier drains).
// global_load_lds w=16, row-major chunks (8 lanes = one row's 128B, full 64B
// lines), LDS slot = row*8 + (kb ^ (row&7)) XOR swizzle. Tail rows read past
// M into adjacent ws slabs (valid memory); store is bounded.
__global__ __launch_bounds__(512, 2)
void gemm_fused(const unsigned short* __restrict__ A1,
                const unsigned short* __restrict__ A2,
                const unsigned short* __restrict__ B1t,
                const unsigned short* __restrict__ B2t,
                const float* __restrict__ bias,
                unsigned short* __restrict__ C,
                int M, int do_relu) {
    __shared__ __align__(16) unsigned short As[8192];   // 128 rows x 8 chunks x 8
    __shared__ __align__(16) unsigned short Bs[16384];  // 256 rows x 8 chunks x 8

    const int t    = threadIdx.x;
    const int m0   = blockIdx.x * 128;
    const int lane = t & 63, wid = t >> 6;
    const int wm   = (wid >> 2) * 64;       // {0,64}
    const int wn   = (wid & 3) * 64;        // {0,64,128,192}
    const int lrow = lane & 15;
    const int kq   = lane >> 4;             // 0..3

    const f32x4 zero4 = {0.f, 0.f, 0.f, 0.f};
    f32x4 acc[4][4];
#pragma unroll
    for (int i = 0; i < 4; ++i)
#pragma unroll
        for (int j = 0; j < 4; ++j) acc[i][j] = zero4;

    for (int it = 0; it < 8; ++it) {        // K = 512 virtual (2 x 256), BK = 64
        const unsigned short* __restrict__ Ab = (it < 4) ? A1 : A2;
        const unsigned short* __restrict__ Bb = (it < 4) ? B1t : B2t;
        int ko = (it * 64) & 255;

        // stage A: 2 x 16B per thread; B: 4 x 16B per thread
#pragma unroll
        for (int i = 0; i < 2; ++i) {
            int q   = t + i * 512;          // 0..1023
            int row = q >> 3;
            int kb  = (q & 7) ^ (row & 7);
            const unsigned short* ga = Ab + (size_t)(m0 + row) * 256 + ko + kb * 8;
            __builtin_amdgcn_global_load_lds((gu32*)ga, (lu32*)(As + q * 8), 16, 0, 0);
        }
#pragma unroll
        for (int i = 0; i < 4; ++i) {
            int q   = t + i * 512;          // 0..2047
            int row = q >> 3;
            int kb  = (q & 7) ^ (row & 7);
            const unsigned short* gb = Bb + (size_t)row * 256 + ko + kb * 8;
            __builtin_amdgcn_global_load_lds((gu32*)gb, (lu32*)(Bs + q * 8), 16, 0, 0);
        }
        __syncthreads();

#pragma unroll
        for (int s = 0; s < 2; ++s) {       // two 32-k MFMA steps per BK=64
            int kqp = s * 4 + kq;
            bf16x8 af[4], bfr[4];
#pragma unroll
            for (int mi = 0; mi < 4; ++mi) {
                int r = wm + mi * 16 + lrow;
                int slot = r * 8 + (kqp ^ (lrow & 7));
                uint4 u = *(const uint4*)(As + slot * 8);
                af[mi] = __builtin_bit_cast(bf16x8, u);
            }
#pragma unroll
            for (int ni = 0; ni < 4; ++ni) {
                int r = wn + ni * 16 + lrow;
                int slot = r * 8 + (kqp ^ (lrow & 7));
                uint4 u = *(const uint4*)(Bs + slot * 8);
                bfr[ni] = __builtin_bit_cast(bf16x8, u);
            }
#pragma unroll
            for (int mi = 0; mi < 4; ++mi)
#pragma unroll
                for (int ni = 0; ni < 4; ++ni)
                    acc[mi][ni] = __builtin_amdgcn_mfma_f32_16x16x32_bf16(
                        af[mi], bfr[ni], acc[mi][ni], 0, 0, 0);
        }
        __syncthreads();
    }

    // epilogue: D mapping col = lane&15, row = (lane>>4)*4 + reg
    const int rbase = (lane >> 4) * 4;
#pragma unroll
    for (int ni = 0; ni < 4; ++ni) {
        int n  = wn + ni * 16 + lrow;
        float bv = bias[n];
#pragma unroll
        for (int mi = 0; mi < 4; ++mi) {
            int mb = m0 + wm + mi * 16 + rbase;
#pragma unroll
            for (int r = 0; r < 4; ++r) {
                int m = mb + r;
                if (m < M) {
                    float v = acc[mi][ni][r] + bv;
                    if (do_relu) v = fmaxf(v, 0.f);
                    C[(size_t)m * 256 + n] = f2bf(v);
                }
            }
        }
    }
}

// ---------- K4: fused pool + root gather + final linear ----------
__global__ void pool_final(const unsigned short* __restrict__ h2,
                           const float* __restrict__ p,
                           const int* __restrict__ graph_ptr,
                           const int* __restrict__ root_ptr,
                           const float* __restrict__ Wlin,
                           const float* __restrict__ blin,
                           float* __restrict__ out) {
    __shared__ float fl[512];
    int g = blockIdx.x;
    int c = threadIdx.x;        // 256 threads = channels
    int s = graph_ptr[g], e = graph_ptr[g + 1];
    float acc = 0.f;
    for (int n = s; n < e; n += 8) {
        int cl = e - 1;
        float w[8]; unsigned short v[8];
#pragma unroll
        for (int j = 0; j < 8; ++j) {
            int nj = n + j;
            int ncj = nj < cl ? nj : cl;
            int nu = __builtin_amdgcn_readfirstlane(ncj);
            w[j] = (nj < e) ? p[nu] : 0.0f;
            v[j] = h2[(size_t)nu * 256 + c];
        }
        SCHED_FENCE();
#pragma unroll
        for (int j = 0; j < 8; ++j)
            acc = fmaf(us2f(v[j]), w[j], acc);
    }
    float cnt = (float)(e - s);
    int root = root_ptr[g];
    fl[c]       = us2f(h2[(size_t)root * 256 + c]);
    fl[256 + c] = acc / fmaxf(cnt, 1.0f);
    __syncthreads();

    int o = threadIdx.x;
    if (o < 128) {
        float s0 = 0.f, s1 = 0.f, s2 = 0.f, s3 = 0.f;
        for (int k = 0; k < 512; k += 4) {
            s0 = fmaf(fl[k + 0], Wlin[(k + 0) * 128 + o], s0);
            s1 = fmaf(fl[k + 1], Wlin[(k + 1) * 128 + o], s1);
            s2 = fmaf(fl[k + 2], Wlin[(k + 2) * 128 + o], s2);
            s3 = fmaf(fl[k + 3], Wlin[(k + 3) * 128 + o], s3);
        }
        out[(size_t)g * 128 + o] = blin[o] + ((s0 + s1) + (s2 + s3));
    }
}

extern "C" void kernel_launch(void* const* d_in, const int* in_sizes, int n_in,
                              void* d_out, int out_size, void* d_ws, size_t ws_size,
                              hipStream_t stream) {
    const float* x        = (const float*)d_in[0];
    const int*   src      = (const int*)d_in[1];
    const int*   dst      = (const int*)d_in[2];
    const float* p        = (const float*)d_in[3];
    const int*   batch    = (const int*)d_in[4];
    const int*   root_ptr = (const int*)d_in[5];
    // d_in[6] = num_graphs (256, hard-coded)
    const float* Wl1  = (const float*)d_in[7];
    const float* Wr1  = (const float*)d_in[8];
    const float* b1   = (const float*)d_in[9];
    const float* Wl2  = (const float*)d_in[10];
    const float* Wr2  = (const float*)d_in[11];
    const float* b2   = (const float*)d_in[12];
    const float* Wlin = (const float*)d_in[13];
    const float* blin = (const float*)d_in[14];
    float* out = (float*)d_out;

    // workspace layout (256B aligned slabs)
    size_t off = 0;
    char* base = (char*)d_ws;
    auto alloc = [&](size_t bytes) -> void* {
        void* q = base + off;
        off += (bytes + 255) & ~(size_t)255;
        return q;
    };
    int*            row_ptr   = (int*)  alloc((N_NODES + 1) * sizeof(int));
    int*            graph_ptr = (int*)  alloc((N_GRAPHS + 1) * sizeof(int));
    float*          inv_deg   = (float*)alloc(N_NODES * sizeof(float));
    unsigned short* Wl1t = (unsigned short*)alloc(256 * 256 * 2);
    unsigned short* Wr1t = (unsigned short*)alloc(256 * 256 * 2);
    unsigned short* Wl2t = (unsigned short*)alloc(256 * 256 * 2);
    unsigned short* Wr2t = (unsigned short*)alloc(256 * 256 * 2);
    unsigned short* xb   = (unsigned short*)alloc((size_t)N_NODES * 256 * 2);
    unsigned short* aggb = (unsigned short*)alloc((size_t)N_NODES * 256 * 2);
    unsigned short* h1   = (unsigned short*)alloc((size_t)N_NODES * 256 * 2);
    unsigned short* h2   = (unsigned short*)alloc((size_t)N_NODES * 256 * 2);
    (void)ws_size; (void)n_in; (void)in_sizes; (void)out_size;

    preprocess<<<13720, 256, 0, stream>>>(x, xb, Wl1, Wr1, Wl2, Wr2,
                                          Wl1t, Wr1t, Wl2t, Wr2t,
                                          dst, batch, row_ptr, graph_ptr, inv_deg);

    dim3 ggrid((N_NODES + 127) / 128);

    // conv1: h1 = relu(agg(x)@Wl1 + x@Wr1 + b1)
    aggregate<<<N_NODES / 4, 256, 0, stream>>>(xb, src, row_ptr, inv_deg, aggb);
    gemm_fused<<<ggrid, 512, 0, stream>>>(aggb, xb, Wl1t, Wr1t, b1, h1, N_NODES, 1);

    // conv2: h2 = agg(h1)@Wl2 + h1@Wr2 + b2
    aggregate<<<N_NODES / 4, 256, 0, stream>>>(h1, src, row_ptr, inv_deg, aggb);
    gemm_fused<<<ggrid, 512, 0, stream>>>(aggb, h1, Wl2t, Wr2t, b2, h2, N_NODES, 0);

    // fused pool + root gather + final linear
    pool_final<<<N_GRAPHS, 256, 0, stream>>>(h2, p, graph_ptr, root_ptr,
                                             Wlin, blin, out);
}